// Round 1
// baseline (207.878 us; speedup 1.0000x reference)
//
#include <hip/hip_runtime.h>

#define DIM 512
#define NHEAD 8
#define HDIM 64
#define BATCH 4
#define SEQ 2048
#define MTOT (BATCH*SEQ)
#define SCALE 0.125f

typedef __bf16 bf16_t;
typedef __bf16 bf16x8 __attribute__((ext_vector_type(8)));
typedef __bf16 bf16x4 __attribute__((ext_vector_type(4)));
typedef float f32x4 __attribute__((ext_vector_type(4)));

// ---------------- fp32 -> bf16 convert (memory-bound, float4 loads) ----------------
__global__ __launch_bounds__(256) void cvt_kernel(const float* __restrict__ in,
                                                  bf16_t* __restrict__ out) {
    int i = (blockIdx.x * 256 + threadIdx.x) * 4;
    float4 v = *reinterpret_cast<const float4*>(in + i);
    bf16x4 o;
    o[0] = (bf16_t)v.x; o[1] = (bf16_t)v.y; o[2] = (bf16_t)v.z; o[3] = (bf16_t)v.w;
    *reinterpret_cast<bf16x4*>(out + i) = o;
}

// ---------------- QKV GEMM: C[m][n] = X[m][:] . W[n][:] + bias[n] ----------------
// M=8192, N=1536, K=512. 128x128 tile, BK=64, 4 waves (2x2) x 64x64 each.
// Epilogue scatters to Q [B,H,N,64] (pre-scaled), K [B,H,N,64], V^T [B,H,64,N], all bf16.
__global__ __launch_bounds__(256) void gemm_qkv_kernel(
    const bf16_t* __restrict__ X, const bf16_t* __restrict__ W,
    const float* __restrict__ bias,
    bf16_t* __restrict__ Qo, bf16_t* __restrict__ Ko, bf16_t* __restrict__ Vto)
{
    __shared__ bf16_t As[128][72];   // +8 pad: 144B row stride -> 2-way bank alias (free)
    __shared__ bf16_t Bs[128][72];
    const int tid = threadIdx.x;
    const int wave = tid >> 6, lane = tid & 63;
    const int lhi = lane >> 4, llo = lane & 15;
    const int m0 = blockIdx.x * 128, n0 = blockIdx.y * 128;
    const int wr = (wave >> 1) * 64, wc = (wave & 1) * 64;
    f32x4 acc[4][4] = {};

    for (int k0 = 0; k0 < DIM; k0 += 64) {
        #pragma unroll
        for (int p = 0; p < 4; ++p) {
            int c = p * 256 + tid;
            int r = c >> 3, cc = (c & 7) * 8;
            *reinterpret_cast<uint4*>(&As[r][cc]) =
                *reinterpret_cast<const uint4*>(X + (size_t)(m0 + r) * DIM + k0 + cc);
            *reinterpret_cast<uint4*>(&Bs[r][cc]) =
                *reinterpret_cast<const uint4*>(W + (size_t)(n0 + r) * DIM + k0 + cc);
        }
        __syncthreads();
        #pragma unroll
        for (int ks = 0; ks < 2; ++ks) {
            bf16x8 af[4], bfr[4];
            #pragma unroll
            for (int i = 0; i < 4; ++i)
                af[i] = *reinterpret_cast<const bf16x8*>(&As[wr + i*16 + llo][ks*32 + lhi*8]);
            #pragma unroll
            for (int j = 0; j < 4; ++j)
                bfr[j] = *reinterpret_cast<const bf16x8*>(&Bs[wc + j*16 + llo][ks*32 + lhi*8]);
            #pragma unroll
            for (int i = 0; i < 4; ++i)
                #pragma unroll
                for (int j = 0; j < 4; ++j)
                    acc[i][j] = __builtin_amdgcn_mfma_f32_16x16x32_bf16(af[i], bfr[j], acc[i][j], 0, 0, 0);
        }
        __syncthreads();
    }

    // C/D layout (m89-verified): col = lane&15, row = (lane>>4)*4 + reg
    #pragma unroll
    for (int j = 0; j < 4; ++j) {
        int col = n0 + wc + j*16 + llo;
        int which = col >> 9;          // 0:q 1:k 2:v
        int hh = (col >> 6) & 7;
        int dd = col & 63;
        float bv = bias[col];
        #pragma unroll
        for (int i = 0; i < 4; ++i) {
            #pragma unroll
            for (int r = 0; r < 4; ++r) {
                int m = m0 + wr + i*16 + lhi*4 + r;
                int b = m >> 11, ns = m & 2047;
                float v = acc[i][j][r] + bv;
                size_t bh = (size_t)(b * NHEAD + hh);
                if (which == 0)
                    Qo[(bh * SEQ + ns) * HDIM + dd] = (bf16_t)(v * SCALE);
                else if (which == 1)
                    Ko[(bh * SEQ + ns) * HDIM + dd] = (bf16_t)v;
                else
                    Vto[(bh * HDIM + dd) * SEQ + ns] = (bf16_t)v;
            }
        }
    }
}

// ---------------- Flash attention: per (q-tile 128, bh). 4 waves x 32 q-rows ----------------
__global__ __launch_bounds__(256) void attn_kernel(
    const bf16_t* __restrict__ Q, const bf16_t* __restrict__ K,
    const bf16_t* __restrict__ Vt, bf16_t* __restrict__ O)
{
    __shared__ bf16_t Ks[64][72];        // K tile [key][d]
    __shared__ bf16_t Vs[64][72];        // V^T tile [d][key]
    __shared__ bf16_t Ps[4][32][72];     // per-wave P tile [q][key]
    const int tid = threadIdx.x;
    const int wave = tid >> 6, lane = tid & 63;
    const int lhi = lane >> 4, llo = lane & 15;
    const int qt = blockIdx.x, bh = blockIdx.y;
    const bf16_t* Qb = Q + (size_t)bh * SEQ * HDIM;
    const bf16_t* Kb = K + (size_t)bh * SEQ * HDIM;
    const bf16_t* Vb = Vt + (size_t)bh * HDIM * SEQ;
    const int q0 = qt * 128 + wave * 32;

    // Q fragments hoisted to registers (A-frag: row=lane&15, k=(lane>>4)*8+j)
    bf16x8 aq[2][2];
    #pragma unroll
    for (int mf = 0; mf < 2; ++mf)
        #pragma unroll
        for (int ks = 0; ks < 2; ++ks)
            aq[mf][ks] = *reinterpret_cast<const bf16x8*>(
                Qb + (size_t)(q0 + mf*16 + llo) * HDIM + ks*32 + lhi*8);

    f32x4 acc_o[2][4] = {};
    float mstat[2][4], lstat[2][4];
    #pragma unroll
    for (int mf = 0; mf < 2; ++mf)
        #pragma unroll
        for (int r = 0; r < 4; ++r) { mstat[mf][r] = -1e30f; lstat[mf][r] = 0.f; }

    for (int kt = 0; kt < SEQ / 64; ++kt) {
        #pragma unroll
        for (int p = 0; p < 2; ++p) {
            int c = p * 256 + tid;
            int r = c >> 3, cc = (c & 7) * 8;
            *reinterpret_cast<uint4*>(&Ks[r][cc]) =
                *reinterpret_cast<const uint4*>(Kb + (size_t)(kt*64 + r) * HDIM + cc);
            *reinterpret_cast<uint4*>(&Vs[r][cc]) =
                *reinterpret_cast<const uint4*>(Vb + (size_t)r * SEQ + kt*64 + cc);
        }
        __syncthreads();

        // S = Q K^T  (Q pre-scaled)
        f32x4 s[2][4] = {};
        #pragma unroll
        for (int ks = 0; ks < 2; ++ks)
            #pragma unroll
            for (int nf = 0; nf < 4; ++nf) {
                bf16x8 bk = *reinterpret_cast<const bf16x8*>(&Ks[nf*16 + llo][ks*32 + lhi*8]);
                #pragma unroll
                for (int mf = 0; mf < 2; ++mf)
                    s[mf][nf] = __builtin_amdgcn_mfma_f32_16x16x32_bf16(aq[mf][ks], bk, s[mf][nf], 0, 0, 0);
            }

        // online softmax; row stats shared across the 16 lanes of a (lane>>4) group
        #pragma unroll
        for (int mf = 0; mf < 2; ++mf) {
            #pragma unroll
            for (int r = 0; r < 4; ++r) {
                float mx = fmaxf(fmaxf(s[mf][0][r], s[mf][1][r]), fmaxf(s[mf][2][r], s[mf][3][r]));
                #pragma unroll
                for (int d = 1; d < 16; d <<= 1) mx = fmaxf(mx, __shfl_xor(mx, d, 64));
                float mold = mstat[mf][r];
                float mn = fmaxf(mold, mx);
                float alpha = __expf(mold - mn);
                float rs = 0.f;
                #pragma unroll
                for (int nf = 0; nf < 4; ++nf) {
                    float pv = __expf(s[mf][nf][r] - mn);
                    s[mf][nf][r] = pv;
                    rs += pv;
                }
                #pragma unroll
                for (int d = 1; d < 16; d <<= 1) rs += __shfl_xor(rs, d, 64);
                lstat[mf][r] = lstat[mf][r] * alpha + rs;
                mstat[mf][r] = mn;
                #pragma unroll
                for (int nf = 0; nf < 4; ++nf) acc_o[mf][nf][r] *= alpha;
            }
        }

        // P -> LDS (reshape C-layout -> A-frag layout)
        #pragma unroll
        for (int mf = 0; mf < 2; ++mf)
            #pragma unroll
            for (int nf = 0; nf < 4; ++nf)
                #pragma unroll
                for (int r = 0; r < 4; ++r)
                    Ps[wave][mf*16 + lhi*4 + r][nf*16 + llo] = (bf16_t)s[mf][nf][r];

        // O += P V
        #pragma unroll
        for (int ks = 0; ks < 2; ++ks) {
            bf16x8 ap[2];
            #pragma unroll
            for (int mf = 0; mf < 2; ++mf)
                ap[mf] = *reinterpret_cast<const bf16x8*>(&Ps[wave][mf*16 + llo][ks*32 + lhi*8]);
            #pragma unroll
            for (int nf = 0; nf < 4; ++nf) {
                bf16x8 bv = *reinterpret_cast<const bf16x8*>(&Vs[nf*16 + llo][ks*32 + lhi*8]);
                #pragma unroll
                for (int mf = 0; mf < 2; ++mf)
                    acc_o[mf][nf] = __builtin_amdgcn_mfma_f32_16x16x32_bf16(ap[mf], bv, acc_o[mf][nf], 0, 0, 0);
            }
        }
        __syncthreads();
    }

    // normalize + write attention output as [B, N, H*64] bf16
    const int b = bh >> 3, h = bh & 7;
    #pragma unroll
    for (int mf = 0; mf < 2; ++mf)
        #pragma unroll
        for (int r = 0; r < 4; ++r) {
            int q = q0 + mf*16 + lhi*4 + r;
            float inv = 1.0f / lstat[mf][r];
            #pragma unroll
            for (int nf = 0; nf < 4; ++nf)
                O[(size_t)(b * SEQ + q) * DIM + h*HDIM + nf*16 + llo] =
                    (bf16_t)(acc_o[mf][nf][r] * inv);
        }
}

// ---------------- Output proj GEMM: out[m][n] = AO[m][:] . Wp[n][:] + bias[n] (fp32 out) ----------------
__global__ __launch_bounds__(256) void gemm_proj_kernel(
    const bf16_t* __restrict__ X, const bf16_t* __restrict__ W,
    const float* __restrict__ bias, float* __restrict__ out)
{
    __shared__ bf16_t As[128][72];
    __shared__ bf16_t Bs[128][72];
    const int tid = threadIdx.x;
    const int wave = tid >> 6, lane = tid & 63;
    const int lhi = lane >> 4, llo = lane & 15;
    const int m0 = blockIdx.x * 128, n0 = blockIdx.y * 128;
    const int wr = (wave >> 1) * 64, wc = (wave & 1) * 64;
    f32x4 acc[4][4] = {};

    for (int k0 = 0; k0 < DIM; k0 += 64) {
        #pragma unroll
        for (int p = 0; p < 4; ++p) {
            int c = p * 256 + tid;
            int r = c >> 3, cc = (c & 7) * 8;
            *reinterpret_cast<uint4*>(&As[r][cc]) =
                *reinterpret_cast<const uint4*>(X + (size_t)(m0 + r) * DIM + k0 + cc);
            *reinterpret_cast<uint4*>(&Bs[r][cc]) =
                *reinterpret_cast<const uint4*>(W + (size_t)(n0 + r) * DIM + k0 + cc);
        }
        __syncthreads();
        #pragma unroll
        for (int ks = 0; ks < 2; ++ks) {
            bf16x8 af[4], bfr[4];
            #pragma unroll
            for (int i = 0; i < 4; ++i)
                af[i] = *reinterpret_cast<const bf16x8*>(&As[wr + i*16 + llo][ks*32 + lhi*8]);
            #pragma unroll
            for (int j = 0; j < 4; ++j)
                bfr[j] = *reinterpret_cast<const bf16x8*>(&Bs[wc + j*16 + llo][ks*32 + lhi*8]);
            #pragma unroll
            for (int i = 0; i < 4; ++i)
                #pragma unroll
                for (int j = 0; j < 4; ++j)
                    acc[i][j] = __builtin_amdgcn_mfma_f32_16x16x32_bf16(af[i], bfr[j], acc[i][j], 0, 0, 0);
        }
        __syncthreads();
    }

    #pragma unroll
    for (int j = 0; j < 4; ++j) {
        int col = n0 + wc + j*16 + llo;
        float bv = bias[col];
        #pragma unroll
        for (int i = 0; i < 4; ++i)
            #pragma unroll
            for (int r = 0; r < 4; ++r) {
                int m = m0 + wr + i*16 + lhi*4 + r;
                out[(size_t)m * DIM + col] = acc[i][j][r] + bv;
            }
    }
}

extern "C" void kernel_launch(void* const* d_in, const int* in_sizes, int n_in,
                              void* d_out, int out_size, void* d_ws, size_t ws_size,
                              hipStream_t stream) {
    const float* x      = (const float*)d_in[0];
    const float* w_qkv  = (const float*)d_in[1];
    const float* b_qkv  = (const float*)d_in[2];
    const float* w_proj = (const float*)d_in[3];
    const float* b_proj = (const float*)d_in[4];
    float* out = (float*)d_out;

    const size_t NX  = (size_t)MTOT * DIM;       // 4,194,304
    const size_t NWQ = (size_t)3 * DIM * DIM;    //   786,432
    const size_t NWP = (size_t)DIM * DIM;        //   262,144
    const size_t NQ  = (size_t)BATCH * NHEAD * SEQ * HDIM; // 4,194,304

    bf16_t* Xb    = (bf16_t*)d_ws;
    bf16_t* Wqkv  = Xb + NX;
    bf16_t* Wproj = Wqkv + NWQ;
    bf16_t* Qb    = Wproj + NWP;
    bf16_t* Kb    = Qb + NQ;
    bf16_t* Vtb   = Kb + NQ;
    bf16_t* AOb   = Vtb + NQ;   // [B, N, 512] bf16

    cvt_kernel<<<(int)(NX  / 1024), 256, 0, stream>>>(x, Xb);
    cvt_kernel<<<(int)(NWQ / 1024), 256, 0, stream>>>(w_qkv, Wqkv);
    cvt_kernel<<<(int)(NWP / 1024), 256, 0, stream>>>(w_proj, Wproj);

    gemm_qkv_kernel<<<dim3(MTOT / 128, (3 * DIM) / 128), 256, 0, stream>>>(
        Xb, Wqkv, b_qkv, Qb, Kb, Vtb);

    attn_kernel<<<dim3(SEQ / 128, BATCH * NHEAD), 256, 0, stream>>>(Qb, Kb, Vtb, AOb);

    gemm_proj_kernel<<<dim3(MTOT / 128, DIM / 128), 256, 0, stream>>>(
        AOb, Wproj, b_proj, out);
}

// Round 2
// 127.956 us; speedup vs baseline: 1.6246x; 1.6246x over previous
//
#include <hip/hip_runtime.h>

#define DIM 512
#define NHEAD 8
#define HDIM 64
#define BATCH 4
#define SEQ 2048
#define MTOT (BATCH*SEQ)
#define SCALE 0.125f
#define LOG2E 1.4426950408889634f

typedef __bf16 bf16_t;
typedef __bf16 bf16x8 __attribute__((ext_vector_type(8)));
typedef __bf16 bf16x4 __attribute__((ext_vector_type(4)));
typedef float f32x4 __attribute__((ext_vector_type(4)));

// ---------------- fp32 -> bf16 convert ----------------
__global__ __launch_bounds__(256) void cvt_kernel(const float* __restrict__ in,
                                                  bf16_t* __restrict__ out) {
    int i = (blockIdx.x * 256 + threadIdx.x) * 4;
    float4 v = *reinterpret_cast<const float4*>(in + i);
    bf16x4 o;
    o[0] = (bf16_t)v.x; o[1] = (bf16_t)v.y; o[2] = (bf16_t)v.z; o[3] = (bf16_t)v.w;
    *reinterpret_cast<bf16x4*>(out + i) = o;
}

// ---------------- QKV GEMM (unchanged except Q pre-scale now SCALE*log2e) ----------------
__global__ __launch_bounds__(256) void gemm_qkv_kernel(
    const bf16_t* __restrict__ X, const bf16_t* __restrict__ W,
    const float* __restrict__ bias,
    bf16_t* __restrict__ Qo, bf16_t* __restrict__ Ko, bf16_t* __restrict__ Vto)
{
    __shared__ bf16_t As[128][72];
    __shared__ bf16_t Bs[128][72];
    const int tid = threadIdx.x;
    const int wave = tid >> 6, lane = tid & 63;
    const int lhi = lane >> 4, llo = lane & 15;
    const int m0 = blockIdx.x * 128, n0 = blockIdx.y * 128;
    const int wr = (wave >> 1) * 64, wc = (wave & 1) * 64;
    f32x4 acc[4][4] = {};

    for (int k0 = 0; k0 < DIM; k0 += 64) {
        #pragma unroll
        for (int p = 0; p < 4; ++p) {
            int c = p * 256 + tid;
            int r = c >> 3, cc = (c & 7) * 8;
            *reinterpret_cast<uint4*>(&As[r][cc]) =
                *reinterpret_cast<const uint4*>(X + (size_t)(m0 + r) * DIM + k0 + cc);
            *reinterpret_cast<uint4*>(&Bs[r][cc]) =
                *reinterpret_cast<const uint4*>(W + (size_t)(n0 + r) * DIM + k0 + cc);
        }
        __syncthreads();
        #pragma unroll
        for (int ks = 0; ks < 2; ++ks) {
            bf16x8 af[4], bfr[4];
            #pragma unroll
            for (int i = 0; i < 4; ++i)
                af[i] = *reinterpret_cast<const bf16x8*>(&As[wr + i*16 + llo][ks*32 + lhi*8]);
            #pragma unroll
            for (int j = 0; j < 4; ++j)
                bfr[j] = *reinterpret_cast<const bf16x8*>(&Bs[wc + j*16 + llo][ks*32 + lhi*8]);
            #pragma unroll
            for (int i = 0; i < 4; ++i)
                #pragma unroll
                for (int j = 0; j < 4; ++j)
                    acc[i][j] = __builtin_amdgcn_mfma_f32_16x16x32_bf16(af[i], bfr[j], acc[i][j], 0, 0, 0);
        }
        __syncthreads();
    }

    #pragma unroll
    for (int j = 0; j < 4; ++j) {
        int col = n0 + wc + j*16 + llo;
        int which = col >> 9;
        int hh = (col >> 6) & 7;
        int dd = col & 63;
        float bv = bias[col];
        #pragma unroll
        for (int i = 0; i < 4; ++i) {
            #pragma unroll
            for (int r = 0; r < 4; ++r) {
                int m = m0 + wr + i*16 + lhi*4 + r;
                int b = m >> 11, ns = m & 2047;
                float v = acc[i][j][r] + bv;
                size_t bh = (size_t)(b * NHEAD + hh);
                if (which == 0)
                    Qo[(bh * SEQ + ns) * HDIM + dd] = (bf16_t)(v * (SCALE * LOG2E));
                else if (which == 1)
                    Ko[(bh * SEQ + ns) * HDIM + dd] = (bf16_t)v;
                else
                    Vto[(bh * HDIM + dd) * SEQ + ns] = (bf16_t)v;
            }
        }
    }
}

// ---------------- Flash attention v2 ----------------
// Per (q-tile 128, bh); 4 waves x 32 q-rows. LDS-double-buffered K/V with
// async reg-staging (issue loads early, write late), 1 barrier/iter.
// Softmax in exp2 domain, defer-max (THR=8 nats), row-sum via ones-MFMA.
__global__ __launch_bounds__(256) void attn_kernel(
    const bf16_t* __restrict__ Q, const bf16_t* __restrict__ K,
    const bf16_t* __restrict__ Vt, bf16_t* __restrict__ O)
{
    __shared__ bf16_t Ks[2][64][72];
    __shared__ bf16_t Vs[2][64][72];
    __shared__ bf16_t Ps[4][32][72];
    const int tid = threadIdx.x;
    const int wave = tid >> 6, lane = tid & 63;
    const int lhi = lane >> 4, llo = lane & 15;
    const int qt = blockIdx.x, bh = blockIdx.y;
    const bf16_t* Qb = Q + (size_t)bh * SEQ * HDIM;
    const bf16_t* Kb = K + (size_t)bh * SEQ * HDIM;
    const bf16_t* Vb = Vt + (size_t)bh * HDIM * SEQ;
    const int q0 = qt * 128 + wave * 32;

    const int sr = tid >> 3;            // 0..31
    const int scc = (tid & 7) * 8;      // 0..56

    // Q fragments (pre-scaled by SCALE*log2e in QKV epilogue)
    bf16x8 aq[2][2];
    #pragma unroll
    for (int mf = 0; mf < 2; ++mf)
        #pragma unroll
        for (int ks = 0; ks < 2; ++ks)
            aq[mf][ks] = *reinterpret_cast<const bf16x8*>(
                Qb + (size_t)(q0 + mf*16 + llo) * HDIM + ks*32 + lhi*8);

    bf16x8 ones;
    #pragma unroll
    for (int j = 0; j < 8; ++j) ones[j] = (bf16_t)1.0f;

    f32x4 acc_o[2][4] = {};
    f32x4 acc_l[2] = {};
    float mstat[2][4];
    #pragma unroll
    for (int mf = 0; mf < 2; ++mf)
        #pragma unroll
        for (int r = 0; r < 4; ++r) mstat[mf][r] = -1e30f;

    const float THR = 8.0f * LOG2E;  // defer-max threshold in log2 units

    uint4 kreg[2], vreg[2];
    // prologue: stage tile 0
    #pragma unroll
    for (int p = 0; p < 2; ++p) {
        kreg[p] = *reinterpret_cast<const uint4*>(Kb + (size_t)(p*32 + sr) * HDIM + scc);
        vreg[p] = *reinterpret_cast<const uint4*>(Vb + (size_t)(p*32 + sr) * SEQ + scc);
    }
    #pragma unroll
    for (int p = 0; p < 2; ++p) {
        *reinterpret_cast<uint4*>(&Ks[0][p*32 + sr][scc]) = kreg[p];
        *reinterpret_cast<uint4*>(&Vs[0][p*32 + sr][scc]) = vreg[p];
    }
    __syncthreads();

    const int NT = SEQ / 64;
    for (int kt = 0; kt < NT; ++kt) {
        const int cur = kt & 1, nxt = cur ^ 1;

        // issue next-tile loads early (latency hides under compute)
        if (kt + 1 < NT) {
            #pragma unroll
            for (int p = 0; p < 2; ++p) {
                kreg[p] = *reinterpret_cast<const uint4*>(
                    Kb + (size_t)((kt+1)*64 + p*32 + sr) * HDIM + scc);
                vreg[p] = *reinterpret_cast<const uint4*>(
                    Vb + (size_t)(p*32 + sr) * SEQ + (kt+1)*64 + scc);
            }
        }

        // S = Q K^T (log2-domain logits)
        f32x4 s[2][4] = {};
        #pragma unroll
        for (int ks = 0; ks < 2; ++ks)
            #pragma unroll
            for (int nf = 0; nf < 4; ++nf) {
                bf16x8 bk = *reinterpret_cast<const bf16x8*>(&Ks[cur][nf*16 + llo][ks*32 + lhi*8]);
                #pragma unroll
                for (int mf = 0; mf < 2; ++mf)
                    s[mf][nf] = __builtin_amdgcn_mfma_f32_16x16x32_bf16(aq[mf][ks], bk, s[mf][nf], 0, 0, 0);
            }

        // lane-local per-row max over the 4 nf values
        float lmax[2][4];
        bool ok = true;
        #pragma unroll
        for (int mf = 0; mf < 2; ++mf)
            #pragma unroll
            for (int r = 0; r < 4; ++r) {
                lmax[mf][r] = fmaxf(fmaxf(s[mf][0][r], s[mf][1][r]),
                                    fmaxf(s[mf][2][r], s[mf][3][r]));
                ok &= (lmax[mf][r] <= mstat[mf][r] + THR);
            }

        if (!__all(ok)) {
            // full rescale path (rare after tile 0)
            #pragma unroll
            for (int mf = 0; mf < 2; ++mf)
                #pragma unroll
                for (int r = 0; r < 4; ++r) {
                    float mx = lmax[mf][r];
                    #pragma unroll
                    for (int d = 1; d < 16; d <<= 1) mx = fmaxf(mx, __shfl_xor(mx, d, 64));
                    float mold = mstat[mf][r];
                    float mn = fmaxf(mold, mx);
                    float alpha = __builtin_amdgcn_exp2f(mold - mn);
                    mstat[mf][r] = mn;
                    #pragma unroll
                    for (int nf = 0; nf < 4; ++nf) acc_o[mf][nf][r] *= alpha;
                    acc_l[mf][r] *= alpha;
                }
        }

        // P = exp2(s - m) -> bf16 -> per-wave LDS (C-layout -> A-frag reshape)
        #pragma unroll
        for (int mf = 0; mf < 2; ++mf)
            #pragma unroll
            for (int nf = 0; nf < 4; ++nf)
                #pragma unroll
                for (int r = 0; r < 4; ++r)
                    Ps[wave][mf*16 + lhi*4 + r][nf*16 + llo] =
                        (bf16_t)__builtin_amdgcn_exp2f(s[mf][nf][r] - mstat[mf][r]);

        // O += P V ; l += P . 1
        #pragma unroll
        for (int ks = 0; ks < 2; ++ks) {
            bf16x8 ap[2];
            #pragma unroll
            for (int mf = 0; mf < 2; ++mf)
                ap[mf] = *reinterpret_cast<const bf16x8*>(&Ps[wave][mf*16 + llo][ks*32 + lhi*8]);
            #pragma unroll
            for (int mf = 0; mf < 2; ++mf)
                acc_l[mf] = __builtin_amdgcn_mfma_f32_16x16x32_bf16(ap[mf], ones, acc_l[mf], 0, 0, 0);
            #pragma unroll
            for (int nf = 0; nf < 4; ++nf) {
                bf16x8 bv = *reinterpret_cast<const bf16x8*>(&Vs[cur][nf*16 + llo][ks*32 + lhi*8]);
                #pragma unroll
                for (int mf = 0; mf < 2; ++mf)
                    acc_o[mf][nf] = __builtin_amdgcn_mfma_f32_16x16x32_bf16(ap[mf], bv, acc_o[mf][nf], 0, 0, 0);
            }
        }

        // write next tile into the other LDS buffer (vmcnt wait lands here)
        if (kt + 1 < NT) {
            #pragma unroll
            for (int p = 0; p < 2; ++p) {
                *reinterpret_cast<uint4*>(&Ks[nxt][p*32 + sr][scc]) = kreg[p];
                *reinterpret_cast<uint4*>(&Vs[nxt][p*32 + sr][scc]) = vreg[p];
            }
        }
        __syncthreads();
    }

    // normalize + write attention output as [B, N, H*64] bf16
    const int b = bh >> 3, h = bh & 7;
    #pragma unroll
    for (int mf = 0; mf < 2; ++mf)
        #pragma unroll
        for (int r = 0; r < 4; ++r) {
            int q = q0 + mf*16 + lhi*4 + r;
            float inv = 1.0f / acc_l[mf][r];
            #pragma unroll
            for (int nf = 0; nf < 4; ++nf)
                O[(size_t)(b * SEQ + q) * DIM + h*HDIM + nf*16 + llo] =
                    (bf16_t)(acc_o[mf][nf][r] * inv);
        }
}

// ---------------- Output proj GEMM ----------------
__global__ __launch_bounds__(256) void gemm_proj_kernel(
    const bf16_t* __restrict__ X, const bf16_t* __restrict__ W,
    const float* __restrict__ bias, float* __restrict__ out)
{
    __shared__ bf16_t As[128][72];
    __shared__ bf16_t Bs[128][72];
    const int tid = threadIdx.x;
    const int wave = tid >> 6, lane = tid & 63;
    const int lhi = lane >> 4, llo = lane & 15;
    const int m0 = blockIdx.x * 128, n0 = blockIdx.y * 128;
    const int wr = (wave >> 1) * 64, wc = (wave & 1) * 64;
    f32x4 acc[4][4] = {};

    for (int k0 = 0; k0 < DIM; k0 += 64) {
        #pragma unroll
        for (int p = 0; p < 4; ++p) {
            int c = p * 256 + tid;
            int r = c >> 3, cc = (c & 7) * 8;
            *reinterpret_cast<uint4*>(&As[r][cc]) =
                *reinterpret_cast<const uint4*>(X + (size_t)(m0 + r) * DIM + k0 + cc);
            *reinterpret_cast<uint4*>(&Bs[r][cc]) =
                *reinterpret_cast<const uint4*>(W + (size_t)(n0 + r) * DIM + k0 + cc);
        }
        __syncthreads();
        #pragma unroll
        for (int ks = 0; ks < 2; ++ks) {
            bf16x8 af[4], bfr[4];
            #pragma unroll
            for (int i = 0; i < 4; ++i)
                af[i] = *reinterpret_cast<const bf16x8*>(&As[wr + i*16 + llo][ks*32 + lhi*8]);
            #pragma unroll
            for (int j = 0; j < 4; ++j)
                bfr[j] = *reinterpret_cast<const bf16x8*>(&Bs[wc + j*16 + llo][ks*32 + lhi*8]);
            #pragma unroll
            for (int i = 0; i < 4; ++i)
                #pragma unroll
                for (int j = 0; j < 4; ++j)
                    acc[i][j] = __builtin_amdgcn_mfma_f32_16x16x32_bf16(af[i], bfr[j], acc[i][j], 0, 0, 0);
        }
        __syncthreads();
    }

    #pragma unroll
    for (int j = 0; j < 4; ++j) {
        int col = n0 + wc + j*16 + llo;
        float bv = bias[col];
        #pragma unroll
        for (int i = 0; i < 4; ++i)
            #pragma unroll
            for (int r = 0; r < 4; ++r) {
                int m = m0 + wr + i*16 + lhi*4 + r;
                out[(size_t)m * DIM + col] = acc[i][j][r] + bv;
            }
    }
}

extern "C" void kernel_launch(void* const* d_in, const int* in_sizes, int n_in,
                              void* d_out, int out_size, void* d_ws, size_t ws_size,
                              hipStream_t stream) {
    const float* x      = (const float*)d_in[0];
    const float* w_qkv  = (const float*)d_in[1];
    const float* b_qkv  = (const float*)d_in[2];
    const float* w_proj = (const float*)d_in[3];
    const float* b_proj = (const float*)d_in[4];
    float* out = (float*)d_out;

    const size_t NX  = (size_t)MTOT * DIM;
    const size_t NWQ = (size_t)3 * DIM * DIM;
    const size_t NWP = (size_t)DIM * DIM;
    const size_t NQ  = (size_t)BATCH * NHEAD * SEQ * HDIM;

    bf16_t* Xb    = (bf16_t*)d_ws;
    bf16_t* Wqkv  = Xb + NX;
    bf16_t* Wproj = Wqkv + NWQ;
    bf16_t* Qb    = Wproj + NWP;
    bf16_t* Kb    = Qb + NQ;
    bf16_t* Vtb   = Kb + NQ;
    bf16_t* AOb   = Vtb + NQ;

    cvt_kernel<<<(int)(NX  / 1024), 256, 0, stream>>>(x, Xb);
    cvt_kernel<<<(int)(NWQ / 1024), 256, 0, stream>>>(w_qkv, Wqkv);
    cvt_kernel<<<(int)(NWP / 1024), 256, 0, stream>>>(w_proj, Wproj);

    gemm_qkv_kernel<<<dim3(MTOT / 128, (3 * DIM) / 128), 256, 0, stream>>>(
        Xb, Wqkv, b_qkv, Qb, Kb, Vtb);

    attn_kernel<<<dim3(SEQ / 128, BATCH * NHEAD), 256, 0, stream>>>(Qb, Kb, Vtb, AOb);

    gemm_proj_kernel<<<dim3(MTOT / 128, DIM / 128), 256, 0, stream>>>(
        AOb, Wproj, b_proj, out);
}